// Round 1
// baseline (1008.077 us; speedup 1.0000x reference)
//
#include <hip/hip_runtime.h>
#include <hip/hip_bf16.h>
#include <math.h>

// Problem constants: B=4, T=512, I=128, H=128 (4H=512)
#define Bq 4
#define Tq 512
#define Hq 128

__device__ __forceinline__ float sigmoid_fast(float x) {
    return 1.0f / (1.0f + __expf(-x));
}
__device__ __forceinline__ float tanh_fast(float x) {
    // tanh(x) = 1 - 2/(exp(2x)+1); saturates correctly for |x| large
    float e = __expf(2.0f * x);
    return 1.0f - 2.0f / (e + 1.0f);
}

// ---------------------------------------------------------------------------
// GEMM "nt": C[m,n] = sum_k A[m,k] * W[n,k] (+bias[n]) (+= C)   K=128 fixed
// A: [2048, lda>=128], W rows stride ldw, C: [2048, 512] (ldc=512)
// grid (32, 8), block 256
// ---------------------------------------------------------------------------
__global__ __launch_bounds__(256) void gemm_nt(const float* __restrict__ A, int lda,
                                               const float* __restrict__ W, int ldw,
                                               const float* __restrict__ bias,
                                               float* __restrict__ C, int acc_flag) {
    __shared__ __align__(16) float As[64][68];
    __shared__ __align__(16) float Ws[64][68];
    int m0 = blockIdx.x * 64, n0 = blockIdx.y * 64;
    int tid = threadIdx.x;
    int tx = tid & 15, ty = tid >> 4;
    float acc[4][4] = {};
    for (int kc = 0; kc < 2; kc++) {
        __syncthreads();
#pragma unroll
        for (int i = 0; i < 4; i++) {
            int idx = tid + 256 * i;
            int r = idx >> 4, c4 = idx & 15;
            *(float4*)(&As[r][c4 * 4]) = *(const float4*)(A + (size_t)(m0 + r) * lda + kc * 64 + c4 * 4);
            *(float4*)(&Ws[r][c4 * 4]) = *(const float4*)(W + (size_t)(n0 + r) * ldw + kc * 64 + c4 * 4);
        }
        __syncthreads();
#pragma unroll
        for (int k4 = 0; k4 < 16; k4++) {
            float4 a[4], wv[4];
#pragma unroll
            for (int i = 0; i < 4; i++) a[i] = *(const float4*)(&As[ty * 4 + i][k4 * 4]);
#pragma unroll
            for (int j = 0; j < 4; j++) wv[j] = *(const float4*)(&Ws[tx * 4 + j][k4 * 4]);
#pragma unroll
            for (int i = 0; i < 4; i++)
#pragma unroll
                for (int j = 0; j < 4; j++)
                    acc[i][j] += a[i].x * wv[j].x + a[i].y * wv[j].y + a[i].z * wv[j].z + a[i].w * wv[j].w;
        }
    }
#pragma unroll
    for (int i = 0; i < 4; i++) {
        int m = m0 + ty * 4 + i;
        int n = n0 + tx * 4;
        float4 v = make_float4(acc[i][0], acc[i][1], acc[i][2], acc[i][3]);
        if (bias) { v.x += bias[n]; v.y += bias[n + 1]; v.z += bias[n + 2]; v.w += bias[n + 3]; }
        if (acc_flag) {
            float4 o = *(const float4*)(C + (size_t)m * 512 + n);
            v.x += o.x; v.y += o.y; v.z += o.z; v.w += o.w;
        }
        *(float4*)(C + (size_t)m * 512 + n) = v;
    }
}

// ---------------------------------------------------------------------------
// GEMM "nn" (dual-A fused): C[m,n] = sum_k A1[m,k]B1[k,n] (+ sum_k A2[m,k]B2[k,n]) + bias
// A: [2048,128]; B: [128,128]; C: [2048,128].  grid (32, 2), block 256
// ---------------------------------------------------------------------------
__global__ __launch_bounds__(256) void gemm_nn(const float* __restrict__ A1, const float* __restrict__ B1,
                                               const float* __restrict__ A2, const float* __restrict__ B2,
                                               const float* __restrict__ bias,
                                               float* __restrict__ C) {
    __shared__ __align__(16) float As[64][68];
    __shared__ __align__(16) float Bs[64][68];
    int m0 = blockIdx.x * 64, n0 = blockIdx.y * 64;
    int tid = threadIdx.x;
    int tx = tid & 15, ty = tid >> 4;
    float acc[4][4] = {};
    for (int src = 0; src < 2; src++) {
        const float* A = src ? A2 : A1;
        const float* Bm = src ? B2 : B1;
        if (!A) break;
        for (int kc = 0; kc < 2; kc++) {
            __syncthreads();
#pragma unroll
            for (int i = 0; i < 4; i++) {
                int idx = tid + 256 * i;
                int r = idx >> 4, c4 = idx & 15;
                *(float4*)(&As[r][c4 * 4]) = *(const float4*)(A + (size_t)(m0 + r) * 128 + kc * 64 + c4 * 4);
                *(float4*)(&Bs[r][c4 * 4]) = *(const float4*)(Bm + (size_t)(kc * 64 + r) * 128 + n0 + c4 * 4);
            }
            __syncthreads();
#pragma unroll
            for (int k4 = 0; k4 < 16; k4++) {
                float4 a[4];
#pragma unroll
                for (int i = 0; i < 4; i++) a[i] = *(const float4*)(&As[ty * 4 + i][k4 * 4]);
#pragma unroll
                for (int kk = 0; kk < 4; kk++) {
                    float4 bv = *(const float4*)(&Bs[k4 * 4 + kk][tx * 4]);
                    float av0 = (kk == 0) ? 0.f : 0.f; (void)av0;
#pragma unroll
                    for (int i = 0; i < 4; i++) {
                        float av = (kk == 0) ? a[i].x : (kk == 1) ? a[i].y : (kk == 2) ? a[i].z : a[i].w;
                        acc[i][0] += av * bv.x;
                        acc[i][1] += av * bv.y;
                        acc[i][2] += av * bv.z;
                        acc[i][3] += av * bv.w;
                    }
                }
            }
        }
    }
#pragma unroll
    for (int i = 0; i < 4; i++) {
        int m = m0 + ty * 4 + i;
        int n = n0 + tx * 4;
        float4 v = make_float4(acc[i][0], acc[i][1], acc[i][2], acc[i][3]);
        if (bias) { v.x += bias[n]; v.y += bias[n + 1]; v.z += bias[n + 2]; v.w += bias[n + 3]; }
        *(float4*)(C + (size_t)m * 128 + n) = v;
    }
}

// ---------------------------------------------------------------------------
// LSTM recurrence (f32). grid = B blocks (1 CU/chain), block = 512 threads.
// Thread (ch, kq): ch=tid&127 channel, kq=tid>>7 k-quarter. Holds weight slice
// for all 4 gates of its channel over k in [32*kq, 32*kq+32) in VGPRs.
// xg: [B,T,512] precomputed input projections (+bias). Hout: [B,T,128].
// ---------------------------------------------------------------------------
__global__ __launch_bounds__(512) void lstm_f32(const float* __restrict__ xg,
                                                const float* __restrict__ Whh,
                                                float* __restrict__ Hout) {
    int b = blockIdx.x;
    int tid = threadIdx.x;
    int ch = tid & 127, kq = tid >> 7;
    __shared__ __align__(16) float h_lds[128];
    __shared__ __align__(16) float4 part[512];

    // weights: gate g row = g*128+ch, k slice [kq*32, kq*32+32)
    float w[4][32];
#pragma unroll
    for (int g = 0; g < 4; g++) {
#pragma unroll
        for (int k4 = 0; k4 < 8; k4++) {
            float4 v = *(const float4*)(Whh + (size_t)(g * 128 + ch) * 128 + kq * 32 + k4 * 4);
            w[g][k4 * 4 + 0] = v.x; w[g][k4 * 4 + 1] = v.y; w[g][k4 * 4 + 2] = v.z; w[g][k4 * 4 + 3] = v.w;
        }
    }
    float c = 0.0f;
    if (tid < 128) h_lds[tid] = 0.0f;
    __syncthreads();

    const float* xgb = xg + (size_t)b * Tq * 512;
    for (int t = 0; t < Tq; t++) {
        // prefetch gate input projections (only channel-owner threads need them)
        float xi = 0.f, xf = 0.f, xgg = 0.f, xo = 0.f;
        if (tid < 128) {
            const float* p = xgb + (size_t)t * 512 + ch;
            xi = p[0]; xf = p[128]; xgg = p[256]; xo = p[384];
        }
        // partial dot over this thread's k-slice for its channel's 4 gates
        float accg[4] = {0.f, 0.f, 0.f, 0.f};
        const float4* h4 = (const float4*)(h_lds + kq * 32);
#pragma unroll
        for (int k4 = 0; k4 < 8; k4++) {
            float4 hv = h4[k4];
#pragma unroll
            for (int g = 0; g < 4; g++) {
                accg[g] += w[g][k4 * 4 + 0] * hv.x + w[g][k4 * 4 + 1] * hv.y
                         + w[g][k4 * 4 + 2] * hv.z + w[g][k4 * 4 + 3] * hv.w;
            }
        }
        part[tid] = make_float4(accg[0], accg[1], accg[2], accg[3]);
        __syncthreads();
        if (tid < 128) {
            float4 p0 = part[ch], p1 = part[ch + 128], p2 = part[ch + 256], p3 = part[ch + 384];
            float gi = p0.x + p1.x + p2.x + p3.x + xi;
            float gf = p0.y + p1.y + p2.y + p3.y + xf;
            float gg = p0.z + p1.z + p2.z + p3.z + xgg;
            float go = p0.w + p1.w + p2.w + p3.w + xo;
            float si = sigmoid_fast(gi), sf = sigmoid_fast(gf), so = sigmoid_fast(go);
            float tg = tanh_fast(gg);
            c = sf * c + si * tg;
            float h = so * tanh_fast(c);
            h_lds[ch] = h;
            Hout[((size_t)b * Tq + t) * Hq + ch] = h;
        }
        __syncthreads();
    }
}

// ---------------------------------------------------------------------------
// Attention: per (t,b) block: scores_s = u . tanh(a_t + c_s), softmax over s,
// R[b,t,:] = sum_s beta_s * Hsh[b,s,:].  (bu omitted: softmax-invariant)
// grid (T, B), block 256
// ---------------------------------------------------------------------------
__global__ __launch_bounds__(256) void attn_kernel(const float* __restrict__ hp_t,
                                                   const float* __restrict__ c_s,
                                                   const float* __restrict__ u,
                                                   const float* __restrict__ Hsh,
                                                   float* __restrict__ R) {
    int t = blockIdx.x, b = blockIdx.y;
    int tid = threadIdx.x;
    __shared__ __align__(16) float a_lds[128];
    __shared__ __align__(16) float u_lds[128];
    __shared__ __align__(16) float sc[512];
    __shared__ __align__(16) float red[256];

    if (tid < 128) {
        a_lds[tid] = hp_t[((size_t)b * Tq + t) * Hq + tid];
        u_lds[tid] = u[tid];
    }
    __syncthreads();

    // scores
#pragma unroll
    for (int r = 0; r < 2; r++) {
        int s = tid + 256 * r;
        const float4* crow = (const float4*)(c_s + ((size_t)b * Tq + s) * Hq);
        float acc = 0.0f;
#pragma unroll 8
        for (int h4 = 0; h4 < 32; h4++) {
            float4 cv = crow[h4];
            float4 av = *(const float4*)(&a_lds[h4 * 4]);
            float4 uv = *(const float4*)(&u_lds[h4 * 4]);
            acc += uv.x * tanh_fast(av.x + cv.x) + uv.y * tanh_fast(av.y + cv.y)
                 + uv.z * tanh_fast(av.z + cv.z) + uv.w * tanh_fast(av.w + cv.w);
        }
        sc[s] = acc;
    }
    __syncthreads();

    // max reduce
    float m = fmaxf(sc[tid], sc[tid + 256]);
    red[tid] = m;
    __syncthreads();
    for (int off = 128; off > 0; off >>= 1) {
        if (tid < off) red[tid] = fmaxf(red[tid], red[tid + off]);
        __syncthreads();
    }
    m = red[0];
    __syncthreads();

    // exp + sum
    float p0 = __expf(sc[tid] - m), p1 = __expf(sc[tid + 256] - m);
    sc[tid] = p0; sc[tid + 256] = p1;
    red[tid] = p0 + p1;
    __syncthreads();
    for (int off = 128; off > 0; off >>= 1) {
        if (tid < off) red[tid] += red[tid + off];
        __syncthreads();
    }
    float rinv = 1.0f / red[0];
    __syncthreads();

    // weighted sum of Hsh
    int h = tid & 127, half = tid >> 7;
    float acc = 0.0f;
    for (int s = half; s < 512; s += 2) {
        acc += sc[s] * Hsh[((size_t)b * Tq + s) * Hq + h];
    }
    red[tid] = acc;
    __syncthreads();
    if (tid < 128) {
        R[((size_t)b * Tq + t) * Hq + tid] = (red[tid] + red[tid + 128]) * rinv;
    }
}

// ---------------------------------------------------------------------------
extern "C" void kernel_launch(void* const* d_in, const int* in_sizes, int n_in,
                              void* d_out, int out_size, void* d_ws, size_t ws_size,
                              hipStream_t stream) {
    const float* x      = (const float*)d_in[0];
    const float* Wih_s  = (const float*)d_in[1];
    const float* Whh_s  = (const float*)d_in[2];
    const float* b_s    = (const float*)d_in[3];
    const float* Wx     = (const float*)d_in[4];
    const float* Wht    = (const float*)d_in[5];
    const float* Whs    = (const float*)d_in[6];
    const float* bs     = (const float*)d_in[7];
    const float* u      = (const float*)d_in[8];
    // d_in[9] = bu: constant shift of scores -> softmax-invariant, unused
    const float* Wih_t  = (const float*)d_in[10];
    const float* Whh_t  = (const float*)d_in[11];
    const float* b_t    = (const float*)d_in[12];
    float* out = (float*)d_out;

    // workspace layout (floats): total 3,145,728 f32 = 12.6 MB
    float* ws    = (float*)d_ws;
    float* xg_s  = ws;                 // [B,T,512]
    float* xg_t  = ws + 1048576;       // [B,T,512]
    float* Hsh   = ws + 2097152;       // [B,T,128]
    float* hp_t  = ws + 2359296;       // [B,T,128]
    float* c_s   = ws + 2621440;       // [B,T,128]
    float* Rbuf  = ws + 2883584;       // [B,T,128]

    dim3 blk(256);
    dim3 g_nt(32, 8);
    dim3 g_nn(32, 2);

    // 1) input projections for both LSTMs
    gemm_nt<<<g_nt, blk, 0, stream>>>(x, 128, Wih_s, 128, b_s, xg_s, 0);
    gemm_nt<<<g_nt, blk, 0, stream>>>(x, 128, Wih_t, 256, b_t, xg_t, 0);

    // 2) shared LSTM
    lstm_f32<<<Bq, 512, 0, stream>>>(xg_s, Whh_s, Hsh);

    // 3) attention precursors: hp_t = Hsh@Wht ; c_s = x@Wx + Hsh@Whs + bs
    gemm_nn<<<g_nn, blk, 0, stream>>>(Hsh, Wht, nullptr, nullptr, nullptr, hp_t);
    gemm_nn<<<g_nn, blk, 0, stream>>>(x, Wx, Hsh, Whs, bs, c_s);

    // 4) attention scores + softmax + weighted sum
    attn_kernel<<<dim3(Tq, Bq), blk, 0, stream>>>(hp_t, c_s, u, Hsh, Rbuf);

    // 5) add R projection into task-LSTM input gates: xg_t += R @ Wih_t[:,128:].T
    gemm_nt<<<g_nt, blk, 0, stream>>>(Rbuf, 128, Wih_t + 128, 256, nullptr, xg_t, 1);

    // 6) task LSTM -> output
    lstm_f32<<<Bq, 512, 0, stream>>>(xg_t, Whh_t, out);
}